// Round 10
// baseline (99.681 us; speedup 1.0000x reference)
//
#include <hip/hip_runtime.h>

#define N_NODES 50000
#define N_EDGES 800000
#define N_FEATS 64
#define EB4     (N_EDGES / 4)     // 200000 int4 groups
#define NBUCK   256               // destination buckets
#define BRANGE  196               // nodes per bucket: 256*196 = 50176 >= 50000
#define CAPB    4096              // records per bucket: mean 3136, +17 sigma
#define BZT     1024              // bucketize block size; 196 blocks * 1024 >= EB4
#define PRT     512               // prep block size
#define HOPT    832               // hop block size: 13 waves, 784 gather lanes
#define MAXREC  (BZT * 4)         // 4096 records max per bucketize block
#define OSTR    256               // offset-array stride per bucket

// Bucketize sort buffers (32 KB, only live in k_bucketize).
struct SmemSort { unsigned buf[MAXREC]; unsigned adr[MAXREC]; };

// ---------------- kernels ----------------

// R1-proven bucketize: LDS counting sort by bucket -> ONE global atomic per
// (block,bucket) reserves a contiguous run -> coalesced compact stream-out.
// Record = (local_dest << 16) | src  (src < 50000 < 2^16, local_dest < 196).
__global__ void __launch_bounds__(BZT) k_bucketize(
    const int* __restrict__ row, const int* __restrict__ col,
    int* __restrict__ gcur, unsigned* __restrict__ recs)
{
    __shared__ SmemSort u;
    __shared__ int s_cnt[NBUCK];
    __shared__ int s_off[NBUCK];
    __shared__ int s_wsum[4];
    __shared__ int s_total;

    const int t = threadIdx.x;
    if (t < NBUCK) s_cnt[t] = 0;
    __syncthreads();

    const int g = blockIdx.x * BZT + t;
    const bool valid = g < EB4;
    int4 c4, r4;
    int bk[4], rk[4];
    if (valid) {
        c4 = ((const int4*)col)[g];
        r4 = ((const int4*)row)[g];
        bk[0] = c4.x / BRANGE; rk[0] = atomicAdd(&s_cnt[bk[0]], 1);
        bk[1] = c4.y / BRANGE; rk[1] = atomicAdd(&s_cnt[bk[1]], 1);
        bk[2] = c4.z / BRANGE; rk[2] = atomicAdd(&s_cnt[bk[2]], 1);
        bk[3] = c4.w / BRANGE; rk[3] = atomicAdd(&s_cnt[bk[3]], 1);
    }
    __syncthreads();

    // 256-entry exclusive prefix sum (4 waves, shuffle scan)
    if (t < NBUCK) {
        const int lane = t & 63;
        const int cnt = s_cnt[t];
        int val = cnt;
        #pragma unroll
        for (int d = 1; d < 64; d <<= 1) {
            int tmp = __shfl_up(val, d);
            if (lane >= d) val += tmp;
        }
        if (lane == 63) s_wsum[t >> 6] = val;
        s_off[t] = val - cnt;
    }
    __syncthreads();
    if (t < NBUCK) {
        const int w4 = t >> 6;
        int base = 0;
        #pragma unroll
        for (int i = 0; i < 3; i++) if (i < w4) base += s_wsum[i];
        s_off[t] += base;
        const int cnt = s_cnt[t];
        s_cnt[t] = cnt ? atomicAdd(&gcur[t], cnt) : 0;   // global run base
        if (t == 0) s_total = s_wsum[0] + s_wsum[1] + s_wsum[2] + s_wsum[3];
    }
    __syncthreads();

    // scatter records into LDS bucket-major with final global addresses
    if (valid) {
        const int cc[4] = {c4.x, c4.y, c4.z, c4.w};
        const int rr[4] = {r4.x, r4.y, r4.z, r4.w};
        #pragma unroll
        for (int i = 0; i < 4; i++) {
            const int b = bk[i];
            const int p = s_off[b] + rk[i];
            const int slot = s_cnt[b] + rk[i];
            u.buf[p] = ((unsigned)(cc[i] - b * BRANGE) << 16) | (unsigned)rr[i];
            u.adr[p] = (slot < CAPB) ? (unsigned)(b * CAPB + slot) : 0xFFFFFFFFu;
        }
    }
    __syncthreads();

    // coalesced compact stream-out (per-bucket runs of consecutive addresses)
    const int total = s_total;
    for (int p = t; p < total; p += BZT) {
        const unsigned a = u.adr[p];
        if (a != 0xFFFFFFFFu) recs[a] = u.buf[p];
    }
}

// Prep: degree histogram (records in registers) -> DEST-SORT via counting
// sort (histogram IS the sort base) -> PUBLISH run offsets (the exclusive
// prefix, so hops can be atomic-free) -> in-place coalesced write-back ->
// dinv -> z0 = dinv * (X @ W^T).
__global__ void __launch_bounds__(PRT) k_prep(
    const int* __restrict__ gcur, unsigned* __restrict__ recs,
    const float* __restrict__ x, const float* __restrict__ w,
    int* __restrict__ offs, float* __restrict__ dinv, float* __restrict__ z0)
{
    __shared__ unsigned s_sorted[CAPB];   // 16 KB
    __shared__ int s_deg[NBUCK];
    __shared__ int s_base[NBUCK];
    __shared__ int s_wsum[4];

    const int t = threadIdx.x;
    const int blk = blockIdx.x;
    if (t < NBUCK) s_deg[t] = 0;
    __syncthreads();

    const int sz = min(gcur[blk], CAPB);

    // load my 8 records (4x uint2) into registers + degree histogram
    const uint2* rb2 = (const uint2*)(recs + (size_t)blk * CAPB);
    uint2 q[4];
    #pragma unroll
    for (int i = 0; i < 4; i++) {
        const int idx = t + i * PRT;      // uint2 index; 2048 covers CAPB
        q[i] = make_uint2(0u, 0u);
        if (2 * idx < sz) {
            q[i] = rb2[idx];
            atomicAdd(&s_deg[q[i].x >> 16], 1);
            if (2 * idx + 1 < sz) atomicAdd(&s_deg[q[i].y >> 16], 1);
        }
    }
    __syncthreads();

    // exclusive prefix over the degree counts (4 waves, shuffle scan)
    if (t < NBUCK) {
        const int lane = t & 63;
        const int c = s_deg[t];
        int v = c;
        #pragma unroll
        for (int d = 1; d < 64; d <<= 1) {
            int tmp = __shfl_up(v, d);
            if (lane >= d) v += tmp;
        }
        if (lane == 63) s_wsum[t >> 6] = v;
        s_base[t] = v - c;
    }
    __syncthreads();
    if (t < NBUCK) {
        const int w4 = t >> 6;
        int base = 0;
        #pragma unroll
        for (int i = 0; i < 3; i++) if (i < w4) base += s_wsum[i];
        s_base[t] += base;
        // publish run starts; s_base[196] == sz acts as the end sentinel
        if (t <= BRANGE) offs[blk * OSTR + t] = s_base[t];
    }
    __syncthreads();

    // counting-sort scatter into LDS (rank via returning atomic on s_base)
    #pragma unroll
    for (int i = 0; i < 4; i++) {
        const int idx = t + i * PRT;
        if (2 * idx < sz) {
            const int p0 = atomicAdd(&s_base[q[i].x >> 16], 1);
            s_sorted[p0] = q[i].x;
            if (2 * idx + 1 < sz) {
                const int p1 = atomicAdd(&s_base[q[i].y >> 16], 1);
                s_sorted[p1] = q[i].y;
            }
        }
    }
    __syncthreads();

    // coalesced in-place write-back (all reads of recs completed above)
    for (int p = t; p < sz; p += PRT)
        recs[(size_t)blk * CAPB + p] = s_sorted[p];

    // dinv + z0 matvec (thread-per-node, 16x float4 chain)
    if (t < BRANGE) {
        const int node = blk * BRANGE + t;
        if (node < N_NODES) {
            const float d = rsqrtf((float)(s_deg[t] + 1));  // +1 self loop
            dinv[node] = d;
            const float4* xr = (const float4*)(x + (size_t)node * N_FEATS);
            const float4* wr = (const float4*)w;
            float a = 0.0f;
            #pragma unroll
            for (int k = 0; k < N_FEATS / 4; k++) {
                const float4 v = xr[k];
                const float4 u = wr[k];
                a += v.x * u.x + v.y * u.y + v.z * u.z + v.w * u.w;
            }
            z0[node] = d * a;
        }
    }
}

// Hop, ATOMIC-FREE: records are dest-sorted with known run offsets. Stage
// records into LDS (coalesced uint4), then a 4-lane quad owns each dest:
// lane j sums records s+j, s+j+4, ... (x4 manual unroll -> 4 independent
// gathers in flight), two shfl_xor adds combine the quad, lane 0 finalizes.
//   FINAL=false: out[i] = dinv^2 * (z[i] + sum)      (emits next z)
//   FINAL=true : out[i] = dinv   * (z[i] + sum) + b
template <bool FINAL>
__global__ void __launch_bounds__(HOPT) k_hop(
    const int* __restrict__ gcur, const unsigned* __restrict__ recs,
    const int* __restrict__ offs, const float* __restrict__ dinv,
    const float* __restrict__ zin, float* __restrict__ out,
    const float* __restrict__ bptr)
{
    __shared__ unsigned rl[CAPB];        // 16 KB record stage
    __shared__ int s_offs[BRANGE + 1];

    const int t = threadIdx.x;
    const int blk = blockIdx.x;
    const int sz  = min(gcur[blk], CAPB);
    const int szw = (sz + 3) >> 2;

    const uint4* rb4 = (const uint4*)(recs + (size_t)blk * CAPB);
    for (int e = t; e < szw; e += HOPT) ((uint4*)rl)[e] = rb4[e];
    if (t <= BRANGE) s_offs[t] = offs[blk * OSTR + t];
    __syncthreads();

    float sum = 0.0f;
    if (t < 4 * BRANGE) {
        const int d = t >> 2;
        const int j = t & 3;
        const int e2 = s_offs[d + 1];
        int k = s_offs[d] + j;
        // 4-deep MLP: 4 LDS record reads -> 4 independent zin gathers
        for (; k + 12 < e2; k += 16) {
            const unsigned r0 = rl[k], r1 = rl[k + 4];
            const unsigned r2 = rl[k + 8], r3 = rl[k + 12];
            sum += zin[r0 & 0xFFFFu] + zin[r1 & 0xFFFFu]
                 + zin[r2 & 0xFFFFu] + zin[r3 & 0xFFFFu];
        }
        for (; k < e2; k += 4) sum += zin[rl[k] & 0xFFFFu];
    }
    // combine the quad (lanes 4q..4q+3 are wave-adjacent)
    sum += __shfl_xor(sum, 1);
    sum += __shfl_xor(sum, 2);

    if (t < 4 * BRANGE && (t & 3) == 0) {
        const int node = blk * BRANGE + (t >> 2);
        if (node < N_NODES) {
            const float d = dinv[node];
            const float v = zin[node] + sum;
            out[node] = FINAL ? (d * v + bptr[0]) : (d * d * v);
        }
    }
}

// ---------------- launch ----------------

extern "C" void kernel_launch(void* const* d_in, const int* in_sizes, int n_in,
                              void* d_out, int out_size, void* d_ws, size_t ws_size,
                              hipStream_t stream) {
    const float* x  = (const float*)d_in[0];   // [N, 64]
    const int*   ei = (const int*)d_in[1];     // [2, E]
    const float* W  = (const float*)d_in[2];   // [1, 64]
    const float* b  = (const float*)d_in[3];   // [1]
    float* out = (float*)d_out;                // [N]

    const int* row = ei;                       // sources
    const int* col = ei + N_EDGES;             // destinations

    // ws: gcur[256] | recs[4 MB] | offs[256*256] | dinv[N] | z0[N] | z1[N]
    int*      gcur = (int*)d_ws;
    unsigned* recs = (unsigned*)(gcur + NBUCK);
    int*      offs = (int*)(recs + (size_t)NBUCK * CAPB);
    float*    dinv = (float*)(offs + NBUCK * OSTR);
    float*    z0   = dinv + N_NODES;
    float*    z1   = z0 + N_NODES;

    // zero bucket cursors (capture-safe DMA memset)
    hipMemsetAsync(gcur, 0, NBUCK * sizeof(int), stream);

    // R1-proven 5-dispatch split: dispatch boundaries are the cheapest
    // grid-wide sync on this chip (beat CG grid.sync, magic barriers, and
    // the 2-dispatch hybrid across R1-R7) and give coherence for free.
    k_bucketize<<<(EB4 + BZT - 1) / BZT, BZT, 0, stream>>>(row, col, gcur, recs);
    k_prep<<<NBUCK, PRT, 0, stream>>>(gcur, recs, x, W, offs, dinv, z0);
    k_hop<false><<<NBUCK, HOPT, 0, stream>>>(gcur, recs, offs, dinv, z0, z1, nullptr);
    k_hop<false><<<NBUCK, HOPT, 0, stream>>>(gcur, recs, offs, dinv, z1, z0, nullptr);
    k_hop<true ><<<NBUCK, HOPT, 0, stream>>>(gcur, recs, offs, dinv, z0, out, b);
}

// Round 11
// 95.816 us; speedup vs baseline: 1.0403x; 1.0403x over previous
//
#include <hip/hip_runtime.h>

#define N_NODES 50000
#define N_EDGES 800000
#define N_FEATS 64
#define EB4     (N_EDGES / 4)     // 200000 int4 groups
#define NBUCK   256               // destination buckets
#define NWRIT   196               // bucketize writer blocks: 196*1024 >= EB4
#define BRANGE  196               // nodes per bucket: 256*196 = 50176 >= 50000
#define CAPB    4096              // records per bucket: mean 3136, +17 sigma
#define BZT     1024              // bucketize block size
#define PRT     1024              // prep block size
#define HOPT    1024              // hop block size
#define MAXREC  (BZT * 4)         // 4096 records max per writer block

// ---------------- shared helpers ----------------

// 256-entry exclusive prefix sum in LDS (4 waves, shuffle scan).
// cnt_in[t] consumed for t<NBUCK; base_out[t] = exclusive prefix; returns
// total via *tot (thread 0 writes). Caller syncs.
__device__ __forceinline__ void scan256(const int* cnt_in, int* base_out,
                                        int* wsum, int* tot) {
    const int t = threadIdx.x;
    if (t < NBUCK) {
        const int lane = t & 63;
        const int c = cnt_in[t];
        int v = c;
        #pragma unroll
        for (int d = 1; d < 64; d <<= 1) {
            int tmp = __shfl_up(v, d);
            if (lane >= d) v += tmp;
        }
        if (lane == 63) wsum[t >> 6] = v;
        base_out[t] = v - c;
    }
    __syncthreads();
    if (t < NBUCK) {
        const int w4 = t >> 6;
        int base = 0;
        #pragma unroll
        for (int i = 0; i < 3; i++) if (i < w4) base += wsum[i];
        base_out[t] += base;
        if (t == 0) *tot = wsum[0] + wsum[1] + wsum[2] + wsum[3];
    }
}

// ---------------- dispatch 1: bucketize ----------------
// Write-only handshake (no gcur atomics, no memset, no scattered runs):
// block g sorts its 4096 records bucket-major in LDS and streams them
// CONTIGUOUSLY to its own region recs2[g*MAXREC..]; publishes per-bucket
// count + local offset (write-before-read -> poison-tolerant).
// Record = (local_dest << 16) | src  (src < 50000 < 2^16, local_dest < 196).
__global__ void __launch_bounds__(BZT) k_bucketize(
    const int* __restrict__ row, const int* __restrict__ col,
    unsigned* __restrict__ cnt, unsigned* __restrict__ off2,
    unsigned* __restrict__ recs2)
{
    __shared__ unsigned sbuf[MAXREC];    // 16 KB bucket-major records
    __shared__ int s_cnt[NBUCK];
    __shared__ int s_off[NBUCK];
    __shared__ int s_wsum[4];
    __shared__ int s_total;

    const int t = threadIdx.x;
    const int blk = blockIdx.x;
    if (t < NBUCK) s_cnt[t] = 0;
    __syncthreads();

    const int g = blk * BZT + t;
    const bool valid = g < EB4;
    int4 c4, r4;
    int bk[4], rk[4];
    if (valid) {
        c4 = ((const int4*)col)[g];
        r4 = ((const int4*)row)[g];
        bk[0] = c4.x / BRANGE; rk[0] = atomicAdd(&s_cnt[bk[0]], 1);
        bk[1] = c4.y / BRANGE; rk[1] = atomicAdd(&s_cnt[bk[1]], 1);
        bk[2] = c4.z / BRANGE; rk[2] = atomicAdd(&s_cnt[bk[2]], 1);
        bk[3] = c4.w / BRANGE; rk[3] = atomicAdd(&s_cnt[bk[3]], 1);
    }
    __syncthreads();

    scan256(s_cnt, s_off, s_wsum, &s_total);
    __syncthreads();

    // publish handshake metadata: [bucket][writer] layout -> prep block b
    // reads 784 B contiguous
    if (t < NBUCK) {
        cnt[t * NBUCK + blk]  = (unsigned)s_cnt[t];
        off2[t * NBUCK + blk] = (unsigned)s_off[t];
    }

    // scatter records into LDS bucket-major
    if (valid) {
        const int cc[4] = {c4.x, c4.y, c4.z, c4.w};
        const int rr[4] = {r4.x, r4.y, r4.z, r4.w};
        #pragma unroll
        for (int i = 0; i < 4; i++) {
            const int b = bk[i];
            sbuf[s_off[b] + rk[i]] =
                ((unsigned)(cc[i] - b * BRANGE) << 16) | (unsigned)rr[i];
        }
    }
    __syncthreads();

    // perfectly coalesced contiguous stream-out to own region
    const int total = s_total;                 // <= MAXREC by construction
    for (int p = t; p < total; p += BZT)
        recs2[(size_t)blk * MAXREC + p] = sbuf[p];
}

// ---------------- dispatch 2: prep ----------------
// Gather own bucket's 196 runs from writer regions -> LDS; then R8-proven:
// degree histogram -> dest-counting-sort -> coalesced writeback -> dinv ->
// z0 = dinv * (X @ W^T). Publishes bsz[blk] (write-only).
__global__ void __launch_bounds__(PRT) k_prep(
    const unsigned* __restrict__ cnt, const unsigned* __restrict__ off2,
    const unsigned* __restrict__ recs2, const float* __restrict__ x,
    const float* __restrict__ w, unsigned* __restrict__ recs,
    int* __restrict__ bsz, float* __restrict__ dinv, float* __restrict__ z0)
{
    __shared__ unsigned s_raw[CAPB];     // 16 KB unsorted records
    __shared__ unsigned s_sorted[CAPB];  // 16 KB dest-sorted records
    __shared__ int s_rcnt[NBUCK];        // per-writer count (196 used)
    __shared__ int s_roff[NBUCK];        // per-writer local offset
    __shared__ int s_rbase[NBUCK];       // exclusive prefix of counts
    __shared__ int s_deg[NBUCK];         // per-dest degree
    __shared__ int s_dbase[NBUCK];
    __shared__ int s_wsum[4];
    __shared__ int s_tot;

    const int t = threadIdx.x;
    const int blk = blockIdx.x;

    // handshake metadata (contiguous 784 B each)
    if (t < NBUCK) {
        s_rcnt[t] = (t < NWRIT) ? (int)cnt[blk * NBUCK + t] : 0;
        s_roff[t] = (t < NWRIT) ? (int)off2[blk * NBUCK + t] : 0;
        s_deg[t] = 0;
    }
    __syncthreads();

    scan256(s_rcnt, s_rbase, s_wsum, &s_tot);
    __syncthreads();
    const int sz = min(s_tot, CAPB);

    // gather 196 runs (avg 16 records): 4 threads per writer, lane-consecutive
    if (t < 4 * NWRIT) {
        const int gw = t >> 2;
        const int j  = t & 3;
        const int rc = s_rcnt[gw];
        const int ro = s_roff[gw];
        const int rb = s_rbase[gw];
        const unsigned* src = recs2 + (size_t)gw * MAXREC + ro;
        for (int i = j; i < rc; i += 4) {
            const int pos = rb + i;
            if (pos < CAPB) s_raw[pos] = src[i];
        }
    }
    __syncthreads();

    // load my 4 records into regs + degree histogram
    unsigned q[4];
    #pragma unroll
    for (int i = 0; i < 4; i++) {
        const int idx = t + i * PRT;
        q[i] = 0u;
        if (idx < sz) {
            q[i] = s_raw[idx];
            atomicAdd(&s_deg[q[i] >> 16], 1);
        }
    }
    __syncthreads();

    scan256(s_deg, s_dbase, s_wsum, &s_tot);
    __syncthreads();

    // counting-sort scatter into s_sorted (rank via returning atomic)
    #pragma unroll
    for (int i = 0; i < 4; i++) {
        const int idx = t + i * PRT;
        if (idx < sz) {
            const int p = atomicAdd(&s_dbase[q[i] >> 16], 1);
            s_sorted[p] = q[i];
        }
    }
    __syncthreads();

    // coalesced writeback of sorted records + publish size (write-only)
    for (int p = t; p < sz; p += PRT)
        recs[(size_t)blk * CAPB + p] = s_sorted[p];
    if (t == 0) bsz[blk] = sz;

    // dinv + z0 matvec (R8-proven thread-per-node, 16x float4 chain)
    if (t < BRANGE) {
        const int node = blk * BRANGE + t;
        if (node < N_NODES) {
            const float d = rsqrtf((float)(s_deg[t] + 1));  // +1 self loop
            dinv[node] = d;
            const float4* xr = (const float4*)(x + (size_t)node * N_FEATS);
            const float4* wr = (const float4*)w;
            float a = 0.0f;
            #pragma unroll
            for (int k = 0; k < N_FEATS / 4; k++) {
                const float4 v = xr[k];
                const float4 u = wr[k];
                a += v.x * u.x + v.y * u.y + v.z * u.z + v.w * u.w;
            }
            z0[node] = d * a;
        }
    }
}

// ---------------- dispatches 3-5: hops (R8-proven form) ----------------
// Records are DEST-SORTED -> each thread's 4 consecutive records are usually
// one run (avg 16): segmented local sum, one LDS atomic per run boundary.
//   FINAL=false: out[i] = dinv^2 * (z[i] + sum)      (emits next z)
//   FINAL=true : out[i] = dinv   * (z[i] + sum) + b
template <bool FINAL>
__global__ void __launch_bounds__(HOPT) k_hop(
    const int* __restrict__ bsz, const unsigned* __restrict__ recs,
    const float* __restrict__ dinv, const float* __restrict__ zin,
    float* __restrict__ out, const float* __restrict__ bptr)
{
    __shared__ float s_acc[BRANGE];
    const int t = threadIdx.x;
    const int blk = blockIdx.x;
    if (t < BRANGE) s_acc[t] = 0.0f;
    __syncthreads();

    const int sz  = min(bsz[blk], CAPB);
    const int sz4 = sz >> 2;
    const uint4* rb4 = (const uint4*)(recs + (size_t)blk * CAPB);
    for (int e = t; e < sz4; e += HOPT) {
        const uint4 r = rb4[e];
        const float v0 = zin[r.x & 0xFFFFu];
        const float v1 = zin[r.y & 0xFFFFu];
        const float v2 = zin[r.z & 0xFFFFu];
        const float v3 = zin[r.w & 0xFFFFu];
        const unsigned d0 = r.x >> 16, d1 = r.y >> 16;
        const unsigned d2 = r.z >> 16, d3 = r.w >> 16;
        float s = v0;
        if (d1 == d0) s += v1; else { atomicAdd(&s_acc[d0], s); s = v1; }
        if (d2 == d1) s += v2; else { atomicAdd(&s_acc[d1], s); s = v2; }
        if (d3 == d2) s += v3; else { atomicAdd(&s_acc[d2], s); s = v3; }
        atomicAdd(&s_acc[d3], s);
    }
    if (t < (sz & 3)) {
        const unsigned r = recs[(size_t)blk * CAPB + (sz4 << 2) + t];
        atomicAdd(&s_acc[r >> 16], zin[r & 0xFFFFu]);
    }
    __syncthreads();

    if (t < BRANGE) {
        const int node = blk * BRANGE + t;
        if (node < N_NODES) {
            const float d = dinv[node];
            const float v = zin[node] + s_acc[t];
            out[node] = FINAL ? (d * v + bptr[0]) : (d * d * v);
        }
    }
}

// ---------------- launch ----------------

extern "C" void kernel_launch(void* const* d_in, const int* in_sizes, int n_in,
                              void* d_out, int out_size, void* d_ws, size_t ws_size,
                              hipStream_t stream) {
    const float* x  = (const float*)d_in[0];   // [N, 64]
    const int*   ei = (const int*)d_in[1];     // [2, E]
    const float* W  = (const float*)d_in[2];   // [1, 64]
    const float* b  = (const float*)d_in[3];   // [1]
    float* out = (float*)d_out;                // [N]

    const int* row = ei;                       // sources
    const int* col = ei + N_EDGES;             // destinations

    // ws: cnt[256*256] | off2[256*256] | recs2[256*4096] | recs[256*4096]
    //   | bsz[256] | dinv[N] | z0[N] | z1[N]   (~9.3 MB, all write-before-read)
    unsigned* cnt   = (unsigned*)d_ws;
    unsigned* off2  = cnt + NBUCK * NBUCK;
    unsigned* recs2 = off2 + NBUCK * NBUCK;
    unsigned* recs  = recs2 + (size_t)NBUCK * MAXREC;
    int*      bsz   = (int*)(recs + (size_t)NBUCK * CAPB);
    float*    dinv  = (float*)(bsz + NBUCK);
    float*    z0    = dinv + N_NODES;
    float*    z1    = z0 + N_NODES;

    // 5 dispatches, NO memset: the write-only handshake (cnt/off2/bsz written
    // before read every iteration) is poison-tolerant. Dispatch boundaries
    // are the cheapest grid-wide sync on this chip (R1-R7 evidence).
    k_bucketize<<<NWRIT, BZT, 0, stream>>>(row, col, cnt, off2, recs2);
    k_prep<<<NBUCK, PRT, 0, stream>>>(cnt, off2, recs2, x, W, recs, bsz, dinv, z0);
    k_hop<false><<<NBUCK, HOPT, 0, stream>>>(bsz, recs, dinv, z0, z1, nullptr);
    k_hop<false><<<NBUCK, HOPT, 0, stream>>>(bsz, recs, dinv, z1, z0, nullptr);
    k_hop<true ><<<NBUCK, HOPT, 0, stream>>>(bsz, recs, dinv, z0, out, b);
}